// Round 4
// baseline (118.574 us; speedup 1.0000x reference)
//
#include <hip/hip_runtime.h>

// SOM BMU: argmin_m (w_sq[m] - 2*dot(x,w[m])) -> (idx/128, idx%128).
// f16 hi/lo split (3 MFMAs per fp32 product), tile-major intermediate layout
// (conflict-free LDS), phase-split pipeline with raw barriers + counted waits
// + setprio (T3/T4/T5), atomicMin(u64) argmin.

#define B_ROWS 4096
#define M_COLS 16384
#define KF 256
#define BM 128
#define BN 128
#define NCHUNK 16
#define NSTEP 64          // 8 col-tiles * 8 k-steps (BK=32)

typedef _Float16 f16x8 __attribute__((ext_vector_type(8)));
typedef float f32x4 __attribute__((ext_vector_type(4)));
typedef unsigned long long u64;

#define GLOAD16(gsrc, ldst) \
  __builtin_amdgcn_global_load_lds((const __attribute__((address_space(1))) void*)(gsrc), \
                                   (__attribute__((address_space(3))) void*)(ldst), 16, 0, 0)

#define BAR()        asm volatile("s_barrier" ::: "memory")
#define WAIT_LGKM0() do { asm volatile("s_waitcnt lgkmcnt(0)" ::: "memory"); \
                          __builtin_amdgcn_sched_barrier(0); } while (0)
#define WAIT_VM0()   asm volatile("s_waitcnt vmcnt(0)" ::: "memory")

// tile-major element index: tiles of 128 rows; per (tile,ks): [kch=4][r=128][kk=8] = 8KB
__device__ __forceinline__ size_t tm_idx(int tile, int ks, int kch, int r) {
    return ((((size_t)(tile * 8 + ks)) * 4 + kch) * 128 + r) * 8;
}

// ---------------- kernel 1: split W -> tile-major f16 hi/lo + w_sq ----------------
__global__ __launch_bounds__(256) void som_split_w(const float* __restrict__ wt,
                                                   _Float16* __restrict__ whi,
                                                   _Float16* __restrict__ wlo,
                                                   float* __restrict__ wsq) {
    const int gid = blockIdx.x * 256 + threadIdx.x;
    const int row = gid >> 5;          // 32 threads per row
    const int kg = gid & 31;           // 8-element k-group
    const float4 v0 = *reinterpret_cast<const float4*>(wt + (size_t)row * KF + kg * 8);
    const float4 v1 = *reinterpret_cast<const float4*>(wt + (size_t)row * KF + kg * 8 + 4);
    const float vv[8] = {v0.x, v0.y, v0.z, v0.w, v1.x, v1.y, v1.z, v1.w};
    f16x8 h, l;
    float s = 0.0f;
#pragma unroll
    for (int j = 0; j < 8; ++j) {
        h[j] = (_Float16)vv[j];
        l[j] = (_Float16)(vv[j] - (float)h[j]);
        s += vv[j] * vv[j];
    }
    const size_t e = tm_idx(row >> 7, kg >> 2, kg & 3, row & 127);
    *reinterpret_cast<f16x8*>(whi + e) = h;
    *reinterpret_cast<f16x8*>(wlo + e) = l;
#pragma unroll
    for (int off = 16; off > 0; off >>= 1) s += __shfl_down(s, off, 64);
    if (kg == 0) wsq[row] = s;   // valid in lanes 0 and 32 (one row each)
}

// ---------------- kernel 2: split X -> tile-major f16 hi/lo; init part ----------------
__global__ __launch_bounds__(256) void som_split_x(const float* __restrict__ xb,
                                                   _Float16* __restrict__ xhi,
                                                   _Float16* __restrict__ xlo,
                                                   u64* __restrict__ part) {
    const int gid = blockIdx.x * 256 + threadIdx.x;
    if (gid < B_ROWS) part[gid] = ~0ull;
    const int row = gid >> 5;
    const int kg = gid & 31;
    const float4 v0 = *reinterpret_cast<const float4*>(xb + (size_t)row * KF + kg * 8);
    const float4 v1 = *reinterpret_cast<const float4*>(xb + (size_t)row * KF + kg * 8 + 4);
    const float vv[8] = {v0.x, v0.y, v0.z, v0.w, v1.x, v1.y, v1.z, v1.w};
    f16x8 h, l;
#pragma unroll
    for (int j = 0; j < 8; ++j) {
        h[j] = (_Float16)vv[j];
        l[j] = (_Float16)(vv[j] - (float)h[j]);
    }
    const size_t e = tm_idx(row >> 7, kg >> 2, kg & 3, row & 127);
    *reinterpret_cast<f16x8*>(xhi + e) = h;
    *reinterpret_cast<f16x8*>(xlo + e) = l;
}

// ---------------- kernel 3: MFMA GEMM + fused argmin ----------------
__global__ __launch_bounds__(256, 2) void som_main(const _Float16* __restrict__ xhi,
                                                   const _Float16* __restrict__ xlo,
                                                   const _Float16* __restrict__ whi,
                                                   const _Float16* __restrict__ wlo,
                                                   const float* __restrict__ wsq,
                                                   u64* __restrict__ part) {
    __shared__ _Float16 lds[2][4][4096];   // [buf][Ah,Al,Bh,Bl][kch=4][r=128][kk=8], 64 KB

    const int tid = threadIdx.x;
    const int lane = tid & 63;
    const int frow = lane & 15;
    const int kch = lane >> 4;
    const int wid = tid >> 6;
    const int wr = wid >> 1;      // wave row (0..1): 64 rows
    const int wc = wid & 1;       // wave col (0..1): 64 cols

    // bijective XCD swizzle (512 blocks, 512%8==0)
    const int id = blockIdx.x;
    const int swz = (id & 7) * 64 + (id >> 3);
    const int bx = swz & 31;      // row tile (0..31)
    const int by = swz >> 5;      // col chunk (0..15)
    const int rowbase = bx * BM;

    const int ebase = (tid & 192) * 8;   // wave-uniform LDS base (halves)
    const int tid8 = tid * 8;

    u64 best[16];
#pragma unroll
    for (int i = 0; i < 16; ++i) best[i] = ~0ull;

    f32x4 acc[4][4];

#define STAGE_A(buf_, step_) do {                                             \
    const int ks_ = (step_) & 7;                                              \
    const size_t ab_ = (size_t)(bx * 8 + ks_) * 4096;                         \
    GLOAD16(xhi + ab_ + tid8,        &lds[buf_][0][ebase]);                   \
    GLOAD16(xhi + ab_ + 2048 + tid8, &lds[buf_][0][2048 + ebase]);            \
    GLOAD16(xlo + ab_ + tid8,        &lds[buf_][1][ebase]);                   \
    GLOAD16(xlo + ab_ + 2048 + tid8, &lds[buf_][1][2048 + ebase]);            \
  } while (0)

#define STAGE_B(buf_, step_) do {                                             \
    const int ct_ = (step_) >> 3, ks_ = (step_) & 7;                          \
    const size_t bb_ = (size_t)((by * 8 + ct_) * 8 + ks_) * 4096;             \
    GLOAD16(whi + bb_ + tid8,        &lds[buf_][2][ebase]);                   \
    GLOAD16(whi + bb_ + 2048 + tid8, &lds[buf_][2][2048 + ebase]);            \
    GLOAD16(wlo + bb_ + tid8,        &lds[buf_][3][ebase]);                   \
    GLOAD16(wlo + bb_ + 2048 + tid8, &lds[buf_][3][2048 + ebase]);            \
  } while (0)

    STAGE_A(0, 0);
    STAGE_B(0, 0);
    __syncthreads();          // prologue: full drain once
    int buf = 0;

    for (int step = 0; step < NSTEP; ++step) {
        if ((step & 7) == 0) {
#pragma unroll
            for (int m = 0; m < 4; ++m)
#pragma unroll
                for (int n = 0; n < 4; ++n) acc[m][n] = (f32x4){0.f, 0.f, 0.f, 0.f};
        }

        // ---- phase A: read A-frags + b[0,1]; stage next step; MFMA n=0,1 ----
        f16x8 ah[4], al[4], bh[4], bl[4];
#pragma unroll
        for (int m = 0; m < 4; ++m) {
            const int off = kch * 1024 + (wr * 64 + m * 16 + frow) * 8;
            ah[m] = *reinterpret_cast<const f16x8*>(&lds[buf][0][off]);
            al[m] = *reinterpret_cast<const f16x8*>(&lds[buf][1][off]);
        }
#pragma unroll
        for (int n = 0; n < 2; ++n) {
            const int off = kch * 1024 + (wc * 64 + n * 16 + frow) * 8;
            bh[n] = *reinterpret_cast<const f16x8*>(&lds[buf][2][off]);
            bl[n] = *reinterpret_cast<const f16x8*>(&lds[buf][3][off]);
        }
        if (step < NSTEP - 1) {
            STAGE_A(buf ^ 1, step + 1);
            STAGE_B(buf ^ 1, step + 1);
        }
        BAR();
        WAIT_LGKM0();
        __builtin_amdgcn_s_setprio(1);
#pragma unroll
        for (int n = 0; n < 2; ++n)
#pragma unroll
            for (int m = 0; m < 4; ++m)
                acc[m][n] = __builtin_amdgcn_mfma_f32_16x16x32_f16(ah[m], bh[n], acc[m][n], 0, 0, 0);
#pragma unroll
        for (int n = 0; n < 2; ++n)
#pragma unroll
            for (int m = 0; m < 4; ++m)
                acc[m][n] = __builtin_amdgcn_mfma_f32_16x16x32_f16(ah[m], bl[n], acc[m][n], 0, 0, 0);
#pragma unroll
        for (int n = 0; n < 2; ++n)
#pragma unroll
            for (int m = 0; m < 4; ++m)
                acc[m][n] = __builtin_amdgcn_mfma_f32_16x16x32_f16(al[m], bh[n], acc[m][n], 0, 0, 0);
        __builtin_amdgcn_s_setprio(0);
        BAR();

        // ---- phase B: read b[2,3]; MFMA n=2,3; publish next tile ----
#pragma unroll
        for (int n = 2; n < 4; ++n) {
            const int off = kch * 1024 + (wc * 64 + n * 16 + frow) * 8;
            bh[n] = *reinterpret_cast<const f16x8*>(&lds[buf][2][off]);
            bl[n] = *reinterpret_cast<const f16x8*>(&lds[buf][3][off]);
        }
        BAR();
        WAIT_LGKM0();
        __builtin_amdgcn_s_setprio(1);
#pragma unroll
        for (int n = 2; n < 4; ++n)
#pragma unroll
            for (int m = 0; m < 4; ++m)
                acc[m][n] = __builtin_amdgcn_mfma_f32_16x16x32_f16(ah[m], bh[n], acc[m][n], 0, 0, 0);
#pragma unroll
        for (int n = 2; n < 4; ++n)
#pragma unroll
            for (int m = 0; m < 4; ++m)
                acc[m][n] = __builtin_amdgcn_mfma_f32_16x16x32_f16(ah[m], bl[n], acc[m][n], 0, 0, 0);
#pragma unroll
        for (int n = 2; n < 4; ++n)
#pragma unroll
            for (int m = 0; m < 4; ++m)
                acc[m][n] = __builtin_amdgcn_mfma_f32_16x16x32_f16(al[m], bh[n], acc[m][n], 0, 0, 0);
        __builtin_amdgcn_s_setprio(0);
        WAIT_VM0();           // next tile landed (covered by both MFMA clusters)
        BAR();                // publish buf^1

        if ((step & 7) == 7) {
            // epilogue; C/D: col=lane&15, row=(lane>>4)*4+reg
            const int colbase = by * 1024 + (step >> 3) * 128;
#pragma unroll
            for (int n = 0; n < 4; ++n) {
                const int colg = colbase + wc * 64 + n * 16 + frow;
                const float wq = wsq[colg];
#pragma unroll
                for (int m = 0; m < 4; ++m)
#pragma unroll
                    for (int r = 0; r < 4; ++r) {
                        const float sc = wq - 2.0f * acc[m][n][r];
                        const unsigned int fb = __float_as_uint(sc);
                        const unsigned int key = (fb & 0x80000000u) ? ~fb : (fb | 0x80000000u);
                        const u64 p = ((u64)key << 32) | (unsigned int)colg;
                        if (p < best[m * 4 + r]) best[m * 4 + r] = p;
                    }
            }
        }
        buf ^= 1;
    }

    // reduce across 16 col-lanes, then across the 2 col-waves, then atomicMin
    __syncthreads();
    u64* red = reinterpret_cast<u64*>(&lds[0][0][0]);   // [128 rows][2 wc]
#pragma unroll
    for (int i = 0; i < 16; ++i) {
        u64 b = best[i];
#pragma unroll
        for (int mk = 1; mk <= 8; mk <<= 1) {
            const u64 o = __shfl_xor(b, mk, 64);
            if (o < b) b = o;
        }
        if (frow == 0) {
            const int rl = wr * 64 + (i >> 2) * 16 + kch * 4 + (i & 3);
            red[rl * 2 + wc] = b;
        }
    }
    __syncthreads();
    if (tid < BM) {
        u64 a = red[tid * 2];
        const u64 b2 = red[tid * 2 + 1];
        if (b2 < a) a = b2;
        atomicMin(part + rowbase + tid, a);
    }
#undef STAGE_A
#undef STAGE_B
}

// ---------------- kernel 4: decode ----------------
__global__ __launch_bounds__(256) void som_decode(const u64* __restrict__ part,
                                                  int* __restrict__ out) {
    const int row = blockIdx.x * 256 + threadIdx.x;
    if (row >= B_ROWS) return;
    const int idx = (int)(part[row] & 0xFFFFFFFFu);
    out[2 * row] = idx >> 7;      // idx / 128
    out[2 * row + 1] = idx & 127; // idx % 128
}

extern "C" void kernel_launch(void* const* d_in, const int* in_sizes, int n_in,
                              void* d_out, int out_size, void* d_ws, size_t ws_size,
                              hipStream_t stream) {
    const float* xb = (const float*)d_in[0];   // [4096, 256] fp32
    const float* wt = (const float*)d_in[1];   // [16384, 256] fp32
    int* out = (int*)d_out;                    // [4096, 2] int32

    char* ws = (char*)d_ws;
    _Float16* xhi = (_Float16*)(ws);                                   // 2 MB
    _Float16* xlo = (_Float16*)(ws + (size_t)2 * 1024 * 1024);         // 2 MB
    _Float16* whi = (_Float16*)(ws + (size_t)4 * 1024 * 1024);         // 8 MB
    _Float16* wlo = (_Float16*)(ws + (size_t)12 * 1024 * 1024);        // 8 MB
    float*    wsq = (float*)(ws + (size_t)20 * 1024 * 1024);           // 64 KB
    u64*     part = (u64*)(ws + (size_t)20 * 1024 * 1024 + 65536);     // 32 KB

    som_split_w<<<(M_COLS * 32) / 256, 256, 0, stream>>>(wt, whi, wlo, wsq);
    som_split_x<<<(B_ROWS * 32) / 256, 256, 0, stream>>>(xb, xhi, xlo, part);
    som_main<<<B_ROWS / BM * NCHUNK, 256, 0, stream>>>(xhi, xlo, whi, wlo, wsq, part);
    som_decode<<<B_ROWS / 256, 256, 0, stream>>>(part, out);
}